// Round 5
// baseline (634.600 us; speedup 1.0000x reference)
//
#include <hip/hip_runtime.h>
#include <hip/hip_fp16.h>

#define NB 4
#define NR 256
#define NC 256
#define NCOIL 32
#define NSEG 4
#define NPOL 2
#define OD 276
#define OFF 10
#define NCC 16          // partial chunks = NCOIL/2 (2 coils per stageC block)

typedef float2 c32;

__device__ __forceinline__ c32 cmul(c32 a, c32 b){
  return make_float2(a.x*b.x - a.y*b.y, a.x*b.y + a.y*b.x);
}
__device__ __forceinline__ c32 cmulj(c32 a, c32 b){ // a * conj(b)
  return make_float2(a.x*b.x + a.y*b.y, a.y*b.x - a.x*b.y);
}
// pad every 8 complex to break power-of-2 LDS bank strides
__device__ __forceinline__ int pd(int a){ return a + (a >> 3); }

__device__ __forceinline__ void wsync(){ __builtin_amdgcn_wave_barrier(); }

// tab[k] = exp(-2*pi*i*k/256)
__device__ __forceinline__ void init_tab(c32* tab, int tid){
  float th = (float)tid * 0.0245436926061703f; // 2*pi/256
  float sn, cs;
  sincosf(th, &sn, &cs);
  tab[tid] = make_float2(cs, -sn);
}

// 256-pt FFT, radix-4 Stockham, one wave (64 lanes), 4 complex per lane.
// WAVE-SYNCHRONOUS: b0/b1 must be private to the calling wave.
// xin[i] = x[u+64*i]; xout[t] = X[u+64*t]. DIR=+1 fwd, DIR=-1 unnorm inverse.
template<int DIR>
__device__ __forceinline__ void fft256(const c32* xin, c32* xout,
                                       c32* b0, c32* b1, const c32* tab, int u){
  c32* bufs[2] = { b0, b1 };
  #pragma unroll
  for (int s = 0; s < 4; ++s){
    const int m = 1 << (2*s);
    c32 a0, a1, a2, a3;
    if (s == 0){ a0 = xin[0]; a1 = xin[1]; a2 = xin[2]; a3 = xin[3]; }
    else {
      const c32* src = bufs[(s+1)&1];
      a0 = src[pd(u)]; a1 = src[pd(u+64)]; a2 = src[pd(u+128)]; a3 = src[pd(u+192)];
    }
    c32 s0 = make_float2(a0.x+a2.x, a0.y+a2.y);
    c32 d0 = make_float2(a0.x-a2.x, a0.y-a2.y);
    c32 s1 = make_float2(a1.x+a3.x, a1.y+a3.y);
    c32 d1 = make_float2(a1.x-a3.x, a1.y-a3.y);
    c32 X0 = make_float2(s0.x+s1.x, s0.y+s1.y);
    c32 X2 = make_float2(s0.x-s1.x, s0.y-s1.y);
    c32 X1, X3;
    if (DIR > 0){
      X1 = make_float2(d0.x + d1.y, d0.y - d1.x);  // d0 - i*d1
      X3 = make_float2(d0.x - d1.y, d0.y + d1.x);  // d0 + i*d1
    } else {
      X1 = make_float2(d0.x - d1.y, d0.y + d1.x);
      X3 = make_float2(d0.x + d1.y, d0.y - d1.x);
    }
    int e1 = u & ~(m-1);                 // twiddle exponent
    c32 w1 = tab[e1];
    c32 w2 = tab[(2*e1) & 255];
    c32 w3 = tab[(3*e1) & 255];
    if (DIR < 0){ w1.y = -w1.y; w2.y = -w2.y; w3.y = -w3.y; }
    X1 = cmul(X1, w1); X2 = cmul(X2, w2); X3 = cmul(X3, w3);
    if (s == 3){
      xout[0] = X0; xout[1] = X1; xout[2] = X2; xout[3] = X3;
    } else {
      c32* dst = bufs[s&1];
      int j = u >> (2*s);
      int k = u & (m-1);
      int base = k + 4*m*j;
      dst[pd(base)]      = X0;
      dst[pd(base+m)]    = X1;
      dst[pd(base+2*m)]  = X2;
      dst[pd(base+3*m)]  = X3;
    }
    wsync();
  }
}

// ---------------------------------------------------------------------------
__global__ __launch_bounds__(256) void zero_kernel(float* __restrict__ out, int n){
  int i = blockIdx.x*256 + threadIdx.x;
  if (i < n) out[i] = 0.0f;
}

// ---------------------------------------------------------------------------
// pack_common: for b in [b0, b0+nb):
// img_t[bl][pol][r][c] = crop(x)*(-1)^{r+c}/256 ; w_t[bl][pol*4+seg][r][c];
// m_t[bl][pol*4+seg][c][r].  grid: nb*NR blocks of 256 (thread = c)
__global__ __launch_bounds__(256) void pack_common_kernel(
    int b0,
    const float* __restrict__ x_re, const float* __restrict__ x_im,
    const float* __restrict__ wm_re, const float* __restrict__ wm_im,
    const float* __restrict__ mask,
    c32* __restrict__ img_t, c32* __restrict__ w_t, float* __restrict__ m_t)
{
  int r = blockIdx.x & (NR-1);
  int bl = blockIdx.x >> 8;
  int b = b0 + bl;
  int c = threadIdx.x;
  const size_t PL = (size_t)NR*NC;
  float sc = (((r + c) & 1) ? -1.0f : 1.0f) * (1.0f/256.0f);
  size_t xrow = (((size_t)b*OD) + (r+OFF))*OD + (c+OFF);
  #pragma unroll
  for (int pol = 0; pol < NPOL; ++pol){
    size_t xi = xrow*NPOL + pol;
    img_t[((size_t)(bl*NPOL+pol))*PL + (size_t)r*NC + c] =
        make_float2(x_re[xi]*sc, x_im[xi]*sc);
  }
  size_t wbase = (((size_t)b*NR + r)*NC + c)*(NPOL*NSEG);
  const float4* wre4 = (const float4*)&wm_re[wbase];
  const float4* wim4 = (const float4*)&wm_im[wbase];
  const float4* mk4  = (const float4*)&mask[wbase];
  #pragma unroll
  for (int pol = 0; pol < NPOL; ++pol){
    float4 re = wre4[pol], im = wim4[pol], mk = mk4[pol];
    float rr[4] = {re.x, re.y, re.z, re.w};
    float ii[4] = {im.x, im.y, im.z, im.w};
    float mm[4] = {mk.x, mk.y, mk.z, mk.w};
    #pragma unroll
    for (int seg = 0; seg < NSEG; ++seg){
      int ps = bl*(NPOL*NSEG) + pol*NSEG + seg;
      w_t[(size_t)ps*PL + (size_t)r*NC + c] = make_float2(rr[seg], ii[seg]);
      m_t[(size_t)ps*PL + (size_t)c*NR + r] = mm[seg];
    }
  }
}

// pack_csm: batch b, all coils: c_t[cl][r][c].  grid: NR blocks of 256
__global__ __launch_bounds__(256) void pack_csm_kernel(
    int b,
    const float* __restrict__ csm_re, const float* __restrict__ csm_im,
    c32* __restrict__ c_t)
{
  int r = blockIdx.x;
  int c = threadIdx.x;
  const size_t PL = (size_t)NR*NC;
  size_t base = (((size_t)b*NR + r)*NC + c)*NCOIL;
  c32* cp = c_t + (size_t)r*NC + c;
  for (int cl = 0; cl < NCOIL; cl += 4){
    float4 re = *(const float4*)&csm_re[base + cl];
    float4 im = *(const float4*)&csm_im[base + cl];
    cp[(size_t)(cl+0)*PL] = make_float2(re.x, im.x);
    cp[(size_t)(cl+1)*PL] = make_float2(re.y, im.y);
    cp[(size_t)(cl+2)*PL] = make_float2(re.z, im.z);
    cp[(size_t)(cl+3)*PL] = make_float2(re.w, im.w);
  }
}

// ---------------------------------------------------------------------------
// stage A: g = img*w*csm (scaled/signed already), row-FFT, write T1[p][c][r] fp16
// grid: CH*NPOL*NSEG*16 blocks of 256 (4 waves, 4 rows each)
__global__ __launch_bounds__(256) void stageA_kernel(
    const c32* __restrict__ img_t, const c32* __restrict__ w_t,
    const c32* __restrict__ c_t, __half2* __restrict__ T1)
{
  __shared__ c32 tab[256];
  __shared__ c32 fbuf[4][2][288];
  __shared__ __half2 tile[NC*17];
  int tid = threadIdx.x;
  int u = tid & 63, w = tid >> 6;
  init_tab(tab, tid);
  __syncthreads();
  int bid = blockIdx.x;
  int p  = bid >> 4;           // ((cl*NPOL)+pol)*NSEG+seg
  int rt = bid & 15;
  int seg = p & 3, pol = (p>>2) & 1, cl = p >> 3;

  for (int ri = 0; ri < 4; ++ri){
    int rl = w*4 + ri;
    int r = rt*16 + rl;
    const c32* ir = img_t + ((size_t)pol*NR + r)*NC;
    const c32* wr = w_t  + ((size_t)(pol*NSEG+seg)*NR + r)*NC;
    const c32* cr = c_t  + ((size_t)cl*NR + r)*NC;
    c32 xin[4], xout[4];
    #pragma unroll
    for (int i = 0; i < 4; ++i){
      int c = u + 64*i;
      xin[i] = cmul(cmul(ir[c], wr[c]), cr[c]);
    }
    fft256<1>(xin, xout, fbuf[w][0], fbuf[w][1], tab, u);
    #pragma unroll
    for (int t = 0; t < 4; ++t){
      int c = u + 64*t;
      tile[c*17 + rl] = __floats2half2_rn(xout[t].x, xout[t].y);
    }
  }
  __syncthreads();
  __half2* tp = T1 + (size_t)p*(NR*NC);
  int r0 = rt*16;
  #pragma unroll
  for (int cb = 0; cb < 16; ++cb){
    int cc = w*64 + cb*4 + (u >> 4);
    int rl = u & 15;
    tp[cc*NR + r0 + rl] = tile[cc*17 + rl];
  }
}

// ---------------------------------------------------------------------------
// stage B: per column c: col-FFT per seg, K = sum(mask*X); then per seg':
// H = K*mask, col-iFFT, *(1/256), TRANSPOSE through 8x256 LDS tile, write
// T2[p][r][c] fp16 ROW-MAJOR (packed 32B/thread stores).
// grid: CH*NPOL*32 blocks of 256 (4 waves, 2 columns per wave)
__global__ __launch_bounds__(256) void stageB_kernel(
    const __half2* __restrict__ T1, const float* __restrict__ m_t,
    __half2* __restrict__ T2)
{
  __shared__ c32 tab[256];
  __shared__ c32 fbuf[4][2][288];
  __shared__ __half2 tile[8][256];
  int tid = threadIdx.x, u = tid & 63, w = tid >> 6;
  init_tab(tab, tid);
  __syncthreads();
  int bid = blockIdx.x;
  int ct = bid & 31;
  int g  = bid >> 5;           // cl*NPOL + pol
  int pol = g & 1;
  int c0 = ct*8;
  const size_t PL = (size_t)NR*NC;

  c32 K[2][4];
  #pragma unroll
  for (int j = 0; j < 2; ++j)
    #pragma unroll
    for (int t = 0; t < 4; ++t) K[j][t] = make_float2(0.f, 0.f);

  #pragma unroll 1
  for (int j = 0; j < 2; ++j){
    int col = c0 + w*2 + j;
    #pragma unroll 1
    for (int seg = 0; seg < NSEG; ++seg){
      const __half2* tp = T1 + ((size_t)(g*NSEG+seg))*PL + (size_t)col*NR;
      const float*  mp = m_t + ((size_t)(pol*NSEG+seg))*PL + (size_t)col*NR;
      c32 xin[4], xout[4];
      float mv[4];
      #pragma unroll
      for (int i = 0; i < 4; ++i){
        xin[i] = __half22float2(tp[u + 64*i]);
        mv[i]  = mp[u + 64*i];
      }
      fft256<1>(xin, xout, fbuf[w][0], fbuf[w][1], tab, u);
      #pragma unroll
      for (int t = 0; t < 4; ++t){
        K[j][t].x += mv[t]*xout[t].x;
        K[j][t].y += mv[t]*xout[t].y;
      }
    }
  }
  #pragma unroll 1
  for (int seg = 0; seg < NSEG; ++seg){
    #pragma unroll 1
    for (int j = 0; j < 2; ++j){
      int col = c0 + w*2 + j;
      const float* mp = m_t + ((size_t)(pol*NSEG+seg))*PL + (size_t)col*NR;
      c32 xin[4], xout[4];
      #pragma unroll
      for (int t = 0; t < 4; ++t){
        float mv = mp[u + 64*t];
        xin[t] = make_float2(K[j][t].x*mv, K[j][t].y*mv);
      }
      fft256<-1>(xin, xout, fbuf[w][0], fbuf[w][1], tab, u);
      #pragma unroll
      for (int t = 0; t < 4; ++t)
        tile[w*2+j][u + 64*t] = __floats2half2_rn(xout[t].x*(1.0f/256.0f),
                                                  xout[t].y*(1.0f/256.0f));
    }
    __syncthreads();
    {
      int r = tid;
      unsigned pk[8];
      #pragma unroll
      for (int k = 0; k < 8; ++k){
        __half2 h = tile[k][r];
        pk[k] = *(unsigned*)&h;
      }
      uint4* dst = (uint4*)(T2 + ((size_t)(g*NSEG+seg))*PL + (size_t)r*NC + c0);
      dst[0] = make_uint4(pk[0], pk[1], pk[2], pk[3]);
      dst[1] = make_uint4(pk[4], pk[5], pk[6], pk[7]);
    }
    __syncthreads();
  }
}

// ---------------------------------------------------------------------------
// stage C (partial): row-iFFT from ROW-MAJOR T2, * conj(w)*conj(csm),
// accumulate 2 coils x 4 segs, write fp16 partial[ch][pol][r][c].
// No LDS tile, no block barriers, next-plane register prefetch.
// grid: (CH/2)*NPOL*64 blocks of 256 (4 waves, 1 row each)
__global__ __launch_bounds__(256) void stageC_part_kernel(
    const __half2* __restrict__ T2, const c32* __restrict__ w_t,
    const c32* __restrict__ c_t, __half2* __restrict__ part, int ch0)
{
  __shared__ c32 tab[256];
  __shared__ c32 fbuf[4][2][288];
  int tid = threadIdx.x, u = tid & 63, w = tid >> 6;
  init_tab(tab, tid);
  __syncthreads();
  int bid = blockIdx.x;
  int rq = bid & 63, pol = (bid>>6) & 1, ch = bid >> 7;   // local coil pair
  int r = rq*4 + w;
  const size_t PL = (size_t)NR*NC;

  c32 acc[4];
  #pragma unroll
  for (int t = 0; t < 4; ++t) acc[t] = make_float2(0.f, 0.f);

  __half2 v[4];
  {
    const __half2* rp = T2 + ((size_t)((ch*2*NPOL+pol)*NSEG))*PL + (size_t)r*NC;
    #pragma unroll
    for (int i = 0; i < 4; ++i) v[i] = rp[u + 64*i];
  }
  #pragma unroll 1
  for (int pl = 0; pl < 2*NSEG; ++pl){
    int cl = ch*2 + (pl>>2), seg = pl & 3;
    c32 xin[4], xout[4];
    #pragma unroll
    for (int i = 0; i < 4; ++i) xin[i] = __half22float2(v[i]);
    if (pl < 2*NSEG-1){
      int cl2 = ch*2 + ((pl+1)>>2), seg2 = (pl+1) & 3;
      const __half2* rp = T2 + ((size_t)((cl2*NPOL+pol)*NSEG+seg2))*PL + (size_t)r*NC;
      #pragma unroll
      for (int i = 0; i < 4; ++i) v[i] = rp[u + 64*i];
    }
    fft256<-1>(xin, xout, fbuf[w][0], fbuf[w][1], tab, u);
    const c32* wr = w_t + ((size_t)(pol*NSEG+seg)*NR + r)*NC;
    const c32* cr = c_t + ((size_t)cl*NR + r)*NC;
    #pragma unroll
    for (int t = 0; t < 4; ++t){
      int cp = u + 64*t;
      c32 vv = cmulj(xout[t], wr[cp]);
      vv = cmulj(vv, cr[cp]);
      acc[t].x += vv.x;
      acc[t].y += vv.y;
    }
  }
  __half2* pp = part + ((size_t)((ch0+ch)*NPOL+pol))*PL + (size_t)r*NC;
  #pragma unroll
  for (int t = 0; t < 4; ++t)
    pp[u + 64*t] = __floats2half2_rn(acc[t].x, acc[t].y);
}

// reduceC: out interior = sign * sum over 16 chunks of partial. Plain stores.
// grid: NR blocks of 256 (thread = c, block = r)
__global__ __launch_bounds__(256) void reduceC_kernel(
    int b, const __half2* __restrict__ part, float* __restrict__ out)
{
  int r = blockIdx.x, c = threadIdx.x;
  const size_t PL = (size_t)NR*NC;
  float2 s[NPOL];
  #pragma unroll
  for (int pol = 0; pol < NPOL; ++pol) s[pol] = make_float2(0.f, 0.f);
  #pragma unroll 4
  for (int ch = 0; ch < NCC; ++ch){
    #pragma unroll
    for (int pol = 0; pol < NPOL; ++pol){
      float2 f = __half22float2(part[((size_t)(ch*NPOL+pol))*PL + (size_t)r*NC + c]);
      s[pol].x += f.x; s[pol].y += f.y;
    }
  }
  float sgn = ((r + c) & 1) ? -1.0f : 1.0f;
  float4 o = make_float4(sgn*s[0].x, sgn*s[0].y, sgn*s[1].x, sgn*s[1].y);
  size_t oidx = (((size_t)b*OD + (r+OFF))*OD + (c+OFF));   // float4 units
  ((float4*)out)[oidx] = o;
}

// ---------------------------------------------------------------------------
extern "C" void kernel_launch(void* const* d_in, const int* in_sizes, int n_in,
                              void* d_out, int out_size, void* d_ws, size_t ws_size,
                              hipStream_t stream)
{
  (void)in_sizes; (void)n_in;
  const float* x_re   = (const float*)d_in[0];
  const float* x_im   = (const float*)d_in[1];
  const float* csm_re = (const float*)d_in[2];
  const float* csm_im = (const float*)d_in[3];
  const float* wm_re  = (const float*)d_in[4];
  const float* wm_im  = (const float*)d_in[5];
  const float* mask   = (const float*)d_in[6];

  const size_t PL = (size_t)NR*NC;
  const size_t imgB1 = (size_t)NPOL*PL*sizeof(c32);           // 1 MiB / batch
  const size_t wB1   = (size_t)NPOL*NSEG*PL*sizeof(c32);      // 4 MiB / batch
  const size_t mB1   = (size_t)NPOL*NSEG*PL*sizeof(float);    // 2 MiB / batch
  const size_t csmB1 = (size_t)NCOIL*PL*sizeof(c32);          // 16 MiB / batch
  const size_t partB = (size_t)NCC*NPOL*PL*4;                 // 32 MiB fp16
  const size_t coilB = (size_t)NPOL*NSEG*PL*4;                // 2 MiB fp16 / coil

  const size_t fixed = NB*(imgB1 + wB1 + mB1) + csmB1 + partB; // 76 MiB

  // coil chunk: T1 + T2 = CH * 4 MiB extra.  CH=16 needs 140 MiB (known fit).
  int CH = 32;
  while (CH > 4){
    if (fixed + (size_t)CH*2*coilB <= ws_size) break;
    CH >>= 1;
  }

  char* ws = (char*)d_ws;
  c32* img_t = (c32*)ws;
  c32* w_t   = (c32*)(ws + NB*imgB1);
  float* m_t = (float*)(ws + NB*(imgB1 + wB1));
  c32* c_t   = (c32*)(ws + NB*(imgB1 + wB1 + mB1));
  __half2* part = (__half2*)(ws + NB*(imgB1 + wB1 + mB1) + csmB1);
  __half2* T1 = (__half2*)(ws + fixed);
  __half2* T2 = (__half2*)(ws + fixed + (size_t)CH*coilB);

  float* out = (float*)d_out;
  zero_kernel<<<(out_size + 255)/256, 256, 0, stream>>>(out, out_size);

  pack_common_kernel<<<NB*NR, 256, 0, stream>>>(0, x_re, x_im, wm_re, wm_im,
                                                mask, img_t, w_t, m_t);
  for (int b = 0; b < NB; ++b){
    c32* img_b = img_t + (size_t)b*NPOL*PL;
    c32* w_b   = w_t   + (size_t)b*NPOL*NSEG*PL;
    float* m_b = m_t   + (size_t)b*NPOL*NSEG*PL;
    pack_csm_kernel<<<NR, 256, 0, stream>>>(b, csm_re, csm_im, c_t);
    for (int c0 = 0; c0 < NCOIL; c0 += CH){
      c32* c_b = c_t + (size_t)c0*PL;
      stageA_kernel<<<CH*NPOL*NSEG*16, 256, 0, stream>>>(img_b, w_b, c_b, T1);
      stageB_kernel<<<CH*NPOL*32, 256, 0, stream>>>(T1, m_b, T2);
      stageC_part_kernel<<<(CH/2)*NPOL*64, 256, 0, stream>>>(T2, w_b, c_b,
                                                             part, c0/2);
    }
    reduceC_kernel<<<NR, 256, 0, stream>>>(b, part, out);
  }
}

// Round 6
// 596.304 us; speedup vs baseline: 1.0642x; 1.0642x over previous
//
#include <hip/hip_runtime.h>
#include <hip/hip_fp16.h>

#define NB 4
#define NR 256
#define NC 256
#define NCOIL 32
#define NSEG 4
#define NPOL 2
#define OD 276
#define OFF 10
#define NCC 16          // partial chunks = NCOIL/2 (2 coils per stageC block)

typedef float2 c32;

__device__ __forceinline__ c32 cmul(c32 a, c32 b){
  return make_float2(a.x*b.x - a.y*b.y, a.x*b.y + a.y*b.x);
}
__device__ __forceinline__ c32 cmulj(c32 a, c32 b){ // a * conj(b)
  return make_float2(a.x*b.x + a.y*b.y, a.y*b.x - a.x*b.y);
}
// pad every 16 complex: for stride-64 b64 LDS access each 16-lane group
// rotates across all 16 bank-pairs -> minimum aliasing (conflict-free b64)
__device__ __forceinline__ int pd(int a){ return a + (a >> 4); }

__device__ __forceinline__ void wsync(){ __builtin_amdgcn_wave_barrier(); }

// tab[k] = exp(-2*pi*i*k/256)
__device__ __forceinline__ void init_tab(c32* tab, int tid){
  float th = (float)tid * 0.0245436926061703f; // 2*pi/256
  float sn, cs;
  sincosf(th, &sn, &cs);
  tab[tid] = make_float2(cs, -sn);
}

// 256-pt FFT, radix-4 Stockham, one wave (64 lanes), 4 complex per lane.
// WAVE-SYNCHRONOUS: b0/b1 must be private to the calling wave.
// xin[i] = x[u+64*i]; xout[t] = X[u+64*t]. DIR=+1 fwd, DIR=-1 unnorm inverse.
template<int DIR>
__device__ __forceinline__ void fft256(const c32* xin, c32* xout,
                                       c32* b0, c32* b1, const c32* tab, int u){
  c32* bufs[2] = { b0, b1 };
  #pragma unroll
  for (int s = 0; s < 4; ++s){
    const int m = 1 << (2*s);
    c32 a0, a1, a2, a3;
    if (s == 0){ a0 = xin[0]; a1 = xin[1]; a2 = xin[2]; a3 = xin[3]; }
    else {
      const c32* src = bufs[(s+1)&1];
      a0 = src[pd(u)]; a1 = src[pd(u+64)]; a2 = src[pd(u+128)]; a3 = src[pd(u+192)];
    }
    c32 s0 = make_float2(a0.x+a2.x, a0.y+a2.y);
    c32 d0 = make_float2(a0.x-a2.x, a0.y-a2.y);
    c32 s1 = make_float2(a1.x+a3.x, a1.y+a3.y);
    c32 d1 = make_float2(a1.x-a3.x, a1.y-a3.y);
    c32 X0 = make_float2(s0.x+s1.x, s0.y+s1.y);
    c32 X2 = make_float2(s0.x-s1.x, s0.y-s1.y);
    c32 X1, X3;
    if (DIR > 0){
      X1 = make_float2(d0.x + d1.y, d0.y - d1.x);  // d0 - i*d1
      X3 = make_float2(d0.x - d1.y, d0.y + d1.x);  // d0 + i*d1
    } else {
      X1 = make_float2(d0.x - d1.y, d0.y + d1.x);
      X3 = make_float2(d0.x + d1.y, d0.y - d1.x);
    }
    int e1 = u & ~(m-1);                 // twiddle exponent
    c32 w1 = tab[e1];
    c32 w2 = tab[(2*e1) & 255];
    c32 w3 = tab[(3*e1) & 255];
    if (DIR < 0){ w1.y = -w1.y; w2.y = -w2.y; w3.y = -w3.y; }
    X1 = cmul(X1, w1); X2 = cmul(X2, w2); X3 = cmul(X3, w3);
    if (s == 3){
      xout[0] = X0; xout[1] = X1; xout[2] = X2; xout[3] = X3;
    } else {
      c32* dst = bufs[s&1];
      int j = u >> (2*s);
      int k = u & (m-1);
      int base = k + 4*m*j;
      dst[pd(base)]      = X0;
      dst[pd(base+m)]    = X1;
      dst[pd(base+2*m)]  = X2;
      dst[pd(base+3*m)]  = X3;
    }
    wsync();
  }
}

// ---------------------------------------------------------------------------
__global__ __launch_bounds__(256) void zero_kernel(float* __restrict__ out, int n){
  int i = blockIdx.x*256 + threadIdx.x;
  if (i < n) out[i] = 0.0f;
}

// ---------------------------------------------------------------------------
// pack_common: for b in [b0, b0+nb):
// img_t[bl][pol][r][c] = crop(x)*(-1)^{r+c}/256 ; w_t[bl][pol*4+seg][r][c];
// m_t[bl][pol*4+seg][c][r].  grid: nb*NR blocks of 256 (thread = c)
__global__ __launch_bounds__(256) void pack_common_kernel(
    int b0,
    const float* __restrict__ x_re, const float* __restrict__ x_im,
    const float* __restrict__ wm_re, const float* __restrict__ wm_im,
    const float* __restrict__ mask,
    c32* __restrict__ img_t, c32* __restrict__ w_t, float* __restrict__ m_t)
{
  int r = blockIdx.x & (NR-1);
  int bl = blockIdx.x >> 8;
  int b = b0 + bl;
  int c = threadIdx.x;
  const size_t PL = (size_t)NR*NC;
  float sc = (((r + c) & 1) ? -1.0f : 1.0f) * (1.0f/256.0f);
  size_t xrow = (((size_t)b*OD) + (r+OFF))*OD + (c+OFF);
  #pragma unroll
  for (int pol = 0; pol < NPOL; ++pol){
    size_t xi = xrow*NPOL + pol;
    img_t[((size_t)(bl*NPOL+pol))*PL + (size_t)r*NC + c] =
        make_float2(x_re[xi]*sc, x_im[xi]*sc);
  }
  size_t wbase = (((size_t)b*NR + r)*NC + c)*(NPOL*NSEG);
  const float4* wre4 = (const float4*)&wm_re[wbase];
  const float4* wim4 = (const float4*)&wm_im[wbase];
  const float4* mk4  = (const float4*)&mask[wbase];
  #pragma unroll
  for (int pol = 0; pol < NPOL; ++pol){
    float4 re = wre4[pol], im = wim4[pol], mk = mk4[pol];
    float rr[4] = {re.x, re.y, re.z, re.w};
    float ii[4] = {im.x, im.y, im.z, im.w};
    float mm[4] = {mk.x, mk.y, mk.z, mk.w};
    #pragma unroll
    for (int seg = 0; seg < NSEG; ++seg){
      int ps = bl*(NPOL*NSEG) + pol*NSEG + seg;
      w_t[(size_t)ps*PL + (size_t)r*NC + c] = make_float2(rr[seg], ii[seg]);
      m_t[(size_t)ps*PL + (size_t)c*NR + r] = mm[seg];
    }
  }
}

// pack_csm: batch b, all coils: c_t[cl][r][c].  grid: NR blocks of 256
__global__ __launch_bounds__(256) void pack_csm_kernel(
    int b,
    const float* __restrict__ csm_re, const float* __restrict__ csm_im,
    c32* __restrict__ c_t)
{
  int r = blockIdx.x;
  int c = threadIdx.x;
  const size_t PL = (size_t)NR*NC;
  size_t base = (((size_t)b*NR + r)*NC + c)*NCOIL;
  c32* cp = c_t + (size_t)r*NC + c;
  for (int cl = 0; cl < NCOIL; cl += 4){
    float4 re = *(const float4*)&csm_re[base + cl];
    float4 im = *(const float4*)&csm_im[base + cl];
    cp[(size_t)(cl+0)*PL] = make_float2(re.x, im.x);
    cp[(size_t)(cl+1)*PL] = make_float2(re.y, im.y);
    cp[(size_t)(cl+2)*PL] = make_float2(re.z, im.z);
    cp[(size_t)(cl+3)*PL] = make_float2(re.w, im.w);
  }
}

// ---------------------------------------------------------------------------
// stage A: g = img*w*csm (scaled/signed already), row-FFT, write T1[p][c][r] fp16
// grid: CH*NPOL*NSEG*16 blocks of 256 (4 waves, 4 rows each)
__global__ __launch_bounds__(256) void stageA_kernel(
    const c32* __restrict__ img_t, const c32* __restrict__ w_t,
    const c32* __restrict__ c_t, __half2* __restrict__ T1)
{
  __shared__ c32 tab[256];
  __shared__ c32 fbuf[4][2][272];
  __shared__ __half2 tile[NC*17];
  int tid = threadIdx.x;
  int u = tid & 63, w = tid >> 6;
  init_tab(tab, tid);
  __syncthreads();
  int bid = blockIdx.x;
  int p  = bid >> 4;           // ((cl*NPOL)+pol)*NSEG+seg
  int rt = bid & 15;
  int seg = p & 3, pol = (p>>2) & 1, cl = p >> 3;

  for (int ri = 0; ri < 4; ++ri){
    int rl = w*4 + ri;
    int r = rt*16 + rl;
    const c32* ir = img_t + ((size_t)pol*NR + r)*NC;
    const c32* wr = w_t  + ((size_t)(pol*NSEG+seg)*NR + r)*NC;
    const c32* cr = c_t  + ((size_t)cl*NR + r)*NC;
    c32 xin[4], xout[4];
    #pragma unroll
    for (int i = 0; i < 4; ++i){
      int c = u + 64*i;
      xin[i] = cmul(cmul(ir[c], wr[c]), cr[c]);
    }
    fft256<1>(xin, xout, fbuf[w][0], fbuf[w][1], tab, u);
    #pragma unroll
    for (int t = 0; t < 4; ++t){
      int c = u + 64*t;
      tile[c*17 + rl] = __floats2half2_rn(xout[t].x, xout[t].y);
    }
  }
  __syncthreads();
  __half2* tp = T1 + (size_t)p*(NR*NC);
  int r0 = rt*16;
  #pragma unroll
  for (int cb = 0; cb < 16; ++cb){
    int cc = w*64 + cb*4 + (u >> 4);
    int rl = u & 15;
    tp[cc*NR + r0 + rl] = tile[cc*17 + rl];
  }
}

// ---------------------------------------------------------------------------
// stage B: per column c: col-FFT per seg, K = sum(mask*X); then per seg':
// H = K*mask, col-iFFT, *(1/256), transpose via [16][256] LDS tile, write
// T2[p][r][c] fp16 ROW-MAJOR.  Each thread stores one FULL 64B row-segment
// (16 half2) -> no partial-line write amplification.
// grid: CH*NPOL*16 blocks of 256 (4 waves, 4 columns per wave)
__global__ __launch_bounds__(256) void stageB_kernel(
    const __half2* __restrict__ T1, const float* __restrict__ m_t,
    __half2* __restrict__ T2)
{
  __shared__ c32 tab[256];
  __shared__ c32 fbuf[4][2][272];
  __shared__ __half2 tile[16][256];
  int tid = threadIdx.x, u = tid & 63, w = tid >> 6;
  init_tab(tab, tid);
  __syncthreads();
  int bid = blockIdx.x;
  int ct = bid & 15;           // column panel
  int g  = bid >> 4;           // cl*NPOL + pol
  int pol = g & 1;
  int c0 = ct*16;
  const size_t PL = (size_t)NR*NC;

  c32 K[4][4];
  #pragma unroll
  for (int j = 0; j < 4; ++j)
    #pragma unroll
    for (int t = 0; t < 4; ++t) K[j][t] = make_float2(0.f, 0.f);

  // phase 1: forward column FFTs, accumulate K = sum_seg mask*FFT(col)
  #pragma unroll
  for (int j = 0; j < 4; ++j){
    int col = c0 + w*4 + j;
    #pragma unroll 1
    for (int seg = 0; seg < NSEG; ++seg){
      const __half2* tp = T1 + ((size_t)(g*NSEG+seg))*PL + (size_t)col*NR;
      const float*  mp = m_t + ((size_t)(pol*NSEG+seg))*PL + (size_t)col*NR;
      c32 xin[4], xout[4];
      float mv[4];
      #pragma unroll
      for (int i = 0; i < 4; ++i){
        xin[i] = __half22float2(tp[u + 64*i]);
        mv[i]  = mp[u + 64*i];
      }
      fft256<1>(xin, xout, fbuf[w][0], fbuf[w][1], tab, u);
      #pragma unroll
      for (int t = 0; t < 4; ++t){
        K[j][t].x += mv[t]*xout[t].x;
        K[j][t].y += mv[t]*xout[t].y;
      }
    }
  }
  // phase 2: per seg' re-mask, inverse col FFT, transpose, row-major store
  #pragma unroll 1
  for (int seg = 0; seg < NSEG; ++seg){
    #pragma unroll
    for (int j = 0; j < 4; ++j){
      int col = c0 + w*4 + j;
      const float* mp = m_t + ((size_t)(pol*NSEG+seg))*PL + (size_t)col*NR;
      c32 xin[4], xout[4];
      #pragma unroll
      for (int t = 0; t < 4; ++t){
        float mv = mp[u + 64*t];
        xin[t] = make_float2(K[j][t].x*mv, K[j][t].y*mv);
      }
      fft256<-1>(xin, xout, fbuf[w][0], fbuf[w][1], tab, u);
      #pragma unroll
      for (int t = 0; t < 4; ++t)
        tile[w*4+j][u + 64*t] = __floats2half2_rn(xout[t].x*(1.0f/256.0f),
                                                  xout[t].y*(1.0f/256.0f));
    }
    __syncthreads();
    {
      int r = tid;
      unsigned pk[16];
      #pragma unroll
      for (int k = 0; k < 16; ++k){
        __half2 h = tile[k][r];
        pk[k] = *(unsigned*)&h;
      }
      uint4* dst = (uint4*)(T2 + ((size_t)(g*NSEG+seg))*PL + (size_t)r*NC + c0);
      dst[0] = make_uint4(pk[0],  pk[1],  pk[2],  pk[3]);
      dst[1] = make_uint4(pk[4],  pk[5],  pk[6],  pk[7]);
      dst[2] = make_uint4(pk[8],  pk[9],  pk[10], pk[11]);
      dst[3] = make_uint4(pk[12], pk[13], pk[14], pk[15]);
    }
    __syncthreads();
  }
}

// ---------------------------------------------------------------------------
// stage C (partial): row-iFFT from ROW-MAJOR T2, * conj(w)*conj(csm),
// accumulate 2 coils x 4 segs, write fp16 partial[ch][pol][r][c].
// No LDS tile, no block barriers, next-plane register prefetch.
// grid: (CH/2)*NPOL*64 blocks of 256 (4 waves, 1 row each)
__global__ __launch_bounds__(256) void stageC_part_kernel(
    const __half2* __restrict__ T2, const c32* __restrict__ w_t,
    const c32* __restrict__ c_t, __half2* __restrict__ part, int ch0)
{
  __shared__ c32 tab[256];
  __shared__ c32 fbuf[4][2][272];
  int tid = threadIdx.x, u = tid & 63, w = tid >> 6;
  init_tab(tab, tid);
  __syncthreads();
  int bid = blockIdx.x;
  int rq = bid & 63, pol = (bid>>6) & 1, ch = bid >> 7;   // local coil pair
  int r = rq*4 + w;
  const size_t PL = (size_t)NR*NC;

  c32 acc[4];
  #pragma unroll
  for (int t = 0; t < 4; ++t) acc[t] = make_float2(0.f, 0.f);

  __half2 v[4];
  {
    const __half2* rp = T2 + ((size_t)((ch*2*NPOL+pol)*NSEG))*PL + (size_t)r*NC;
    #pragma unroll
    for (int i = 0; i < 4; ++i) v[i] = rp[u + 64*i];
  }
  #pragma unroll 1
  for (int pl = 0; pl < 2*NSEG; ++pl){
    int cl = ch*2 + (pl>>2), seg = pl & 3;
    c32 xin[4], xout[4];
    #pragma unroll
    for (int i = 0; i < 4; ++i) xin[i] = __half22float2(v[i]);
    if (pl < 2*NSEG-1){
      int cl2 = ch*2 + ((pl+1)>>2), seg2 = (pl+1) & 3;
      const __half2* rp = T2 + ((size_t)((cl2*NPOL+pol)*NSEG+seg2))*PL + (size_t)r*NC;
      #pragma unroll
      for (int i = 0; i < 4; ++i) v[i] = rp[u + 64*i];
    }
    fft256<-1>(xin, xout, fbuf[w][0], fbuf[w][1], tab, u);
    const c32* wr = w_t + ((size_t)(pol*NSEG+seg)*NR + r)*NC;
    const c32* cr = c_t + ((size_t)cl*NR + r)*NC;
    #pragma unroll
    for (int t = 0; t < 4; ++t){
      int cp = u + 64*t;
      c32 vv = cmulj(xout[t], wr[cp]);
      vv = cmulj(vv, cr[cp]);
      acc[t].x += vv.x;
      acc[t].y += vv.y;
    }
  }
  __half2* pp = part + ((size_t)((ch0+ch)*NPOL+pol))*PL + (size_t)r*NC;
  #pragma unroll
  for (int t = 0; t < 4; ++t)
    pp[u + 64*t] = __floats2half2_rn(acc[t].x, acc[t].y);
}

// reduceC: out interior = sign * sum over 16 chunks of partial. Plain stores.
// grid: NR blocks of 256 (thread = c, block = r)
__global__ __launch_bounds__(256) void reduceC_kernel(
    int b, const __half2* __restrict__ part, float* __restrict__ out)
{
  int r = blockIdx.x, c = threadIdx.x;
  const size_t PL = (size_t)NR*NC;
  float2 s[NPOL];
  #pragma unroll
  for (int pol = 0; pol < NPOL; ++pol) s[pol] = make_float2(0.f, 0.f);
  #pragma unroll 4
  for (int ch = 0; ch < NCC; ++ch){
    #pragma unroll
    for (int pol = 0; pol < NPOL; ++pol){
      float2 f = __half22float2(part[((size_t)(ch*NPOL+pol))*PL + (size_t)r*NC + c]);
      s[pol].x += f.x; s[pol].y += f.y;
    }
  }
  float sgn = ((r + c) & 1) ? -1.0f : 1.0f;
  float4 o = make_float4(sgn*s[0].x, sgn*s[0].y, sgn*s[1].x, sgn*s[1].y);
  size_t oidx = (((size_t)b*OD + (r+OFF))*OD + (c+OFF));   // float4 units
  ((float4*)out)[oidx] = o;
}

// ---------------------------------------------------------------------------
extern "C" void kernel_launch(void* const* d_in, const int* in_sizes, int n_in,
                              void* d_out, int out_size, void* d_ws, size_t ws_size,
                              hipStream_t stream)
{
  (void)in_sizes; (void)n_in;
  const float* x_re   = (const float*)d_in[0];
  const float* x_im   = (const float*)d_in[1];
  const float* csm_re = (const float*)d_in[2];
  const float* csm_im = (const float*)d_in[3];
  const float* wm_re  = (const float*)d_in[4];
  const float* wm_im  = (const float*)d_in[5];
  const float* mask   = (const float*)d_in[6];

  const size_t PL = (size_t)NR*NC;
  const size_t imgB1 = (size_t)NPOL*PL*sizeof(c32);           // 1 MiB / batch
  const size_t wB1   = (size_t)NPOL*NSEG*PL*sizeof(c32);      // 4 MiB / batch
  const size_t mB1   = (size_t)NPOL*NSEG*PL*sizeof(float);    // 2 MiB / batch
  const size_t csmB1 = (size_t)NCOIL*PL*sizeof(c32);          // 16 MiB / batch
  const size_t partB = (size_t)NCC*NPOL*PL*4;                 // 32 MiB fp16
  const size_t coilB = (size_t)NPOL*NSEG*PL*4;                // 2 MiB fp16 / coil

  const size_t fixed = NB*(imgB1 + wB1 + mB1) + csmB1 + partB; // 76 MiB

  // coil chunk: T1 + T2 = CH * 4 MiB extra.  CH=16 needs 140 MiB (known fit).
  int CH = 32;
  while (CH > 4){
    if (fixed + (size_t)CH*2*coilB <= ws_size) break;
    CH >>= 1;
  }

  char* ws = (char*)d_ws;
  c32* img_t = (c32*)ws;
  c32* w_t   = (c32*)(ws + NB*imgB1);
  float* m_t = (float*)(ws + NB*(imgB1 + wB1));
  c32* c_t   = (c32*)(ws + NB*(imgB1 + wB1 + mB1));
  __half2* part = (__half2*)(ws + NB*(imgB1 + wB1 + mB1) + csmB1);
  __half2* T1 = (__half2*)(ws + fixed);
  __half2* T2 = (__half2*)(ws + fixed + (size_t)CH*coilB);

  float* out = (float*)d_out;
  zero_kernel<<<(out_size + 255)/256, 256, 0, stream>>>(out, out_size);

  pack_common_kernel<<<NB*NR, 256, 0, stream>>>(0, x_re, x_im, wm_re, wm_im,
                                                mask, img_t, w_t, m_t);
  for (int b = 0; b < NB; ++b){
    c32* img_b = img_t + (size_t)b*NPOL*PL;
    c32* w_b   = w_t   + (size_t)b*NPOL*NSEG*PL;
    float* m_b = m_t   + (size_t)b*NPOL*NSEG*PL;
    pack_csm_kernel<<<NR, 256, 0, stream>>>(b, csm_re, csm_im, c_t);
    for (int c0 = 0; c0 < NCOIL; c0 += CH){
      c32* c_b = c_t + (size_t)c0*PL;
      stageA_kernel<<<CH*NPOL*NSEG*16, 256, 0, stream>>>(img_b, w_b, c_b, T1);
      stageB_kernel<<<CH*NPOL*16, 256, 0, stream>>>(T1, m_b, T2);
      stageC_part_kernel<<<(CH/2)*NPOL*64, 256, 0, stream>>>(T2, w_b, c_b,
                                                             part, c0/2);
    }
    reduceC_kernel<<<NR, 256, 0, stream>>>(b, part, out);
  }
}